// Round 6
// baseline (866.975 us; speedup 1.0000x reference)
//
#include <hip/hip_runtime.h>
#include <hip/hip_fp16.h>

typedef __attribute__((ext_vector_type(8))) short short8;
typedef __attribute__((ext_vector_type(4))) float floatx4;
typedef __attribute__((ext_vector_type(4))) unsigned int uintx4;
typedef __attribute__((ext_vector_type(2))) unsigned int uintx2;
typedef __attribute__((ext_vector_type(4))) int intx4;
typedef __attribute__((ext_vector_type(4))) unsigned short ushortx4;
typedef unsigned int u32;

#define NN 8192
#define KIN 512
#define COUT 256
#define SHIFT 16.0f

#define AS1 __attribute__((address_space(1)))
#define AS3 __attribute__((address_space(3)))

// async global->LDS, 16B per lane; LDS base wave-uniform, lane lands at +lane*16
__device__ __forceinline__ void stage16(const void* g, void* l) {
  __builtin_amdgcn_global_load_lds((const AS1 u32*)g, (AS3 u32*)l, 16, 0, 0);
}

// ---------- helpers ----------
__device__ __forceinline__ unsigned int f2bf(float f) {
  unsigned int u = __float_as_uint(f);
  return (u + 0x7FFFu + ((u >> 16) & 1u)) >> 16;  // RNE round to bf16
}

// pack two fp32 -> bf16 pair (round-half-up + byte-perm; p>=0, never NaN here)
__device__ __forceinline__ u32 pkbf(float lo, float hi) {
  u32 a = __float_as_uint(lo) + 0x8000u;
  u32 b = __float_as_uint(hi) + 0x8000u;
  return __builtin_amdgcn_perm(b, a, 0x07060302u);  // [hi.b3 hi.b2 lo.b3 lo.b2]
}

__device__ __forceinline__ short8 pack8(const float* p) {
  uintx4 w;
  w.x = pkbf(p[0], p[1]);
  w.y = pkbf(p[2], p[3]);
  w.z = pkbf(p[4], p[5]);
  w.w = pkbf(p[6], p[7]);
  union { uintx4 u; short8 s; } cv; cv.u = w;
  return cv.s;
}

// ---------- K1 merged: cast input fp32->bf16, transpose weights (R4 form) ----------
__global__ __launch_bounds__(256)
void k_prep(const float* __restrict__ in, ushortx4* __restrict__ inA4,
            const float* __restrict__ w, unsigned short* __restrict__ wt) {
  int b = blockIdx.x;
  if (b < 4096) {
    int idx = b * 256 + threadIdx.x;
    floatx4 v = ((const floatx4*)in)[idx];
    ushortx4 o;
    o.x = (unsigned short)f2bf(v.x);
    o.y = (unsigned short)f2bf(v.y);
    o.z = (unsigned short)f2bf(v.z);
    o.w = (unsigned short)f2bf(v.w);
    inA4[idx] = o;
  } else {
    int idx = (b - 4096) * 256 + threadIdx.x;
    int k = idx >> 8, c = idx & 255;
    wt[c * KIN + k] = (unsigned short)f2bf(w[idx]);
  }
}

// ---------- K2: h = X*W via MFMA (R4 form: bf16 inA, 256 blocks x 128 thr) ----------
__global__ __launch_bounds__(128)
void k_gemm_h(const unsigned short* __restrict__ inA, const unsigned short* __restrict__ wt,
              const float* __restrict__ a1, const float* __restrict__ a2,
              unsigned short* __restrict__ ht, float* __restrict__ e1, float* __restrict__ e2,
              float* __restrict__ A1, float* __restrict__ A2, u32* __restrict__ e2pk) {
  int wave = threadIdx.x >> 6;          // 0..1
  int lane = threadIdx.x & 63;
  int n = lane & 15, q = lane >> 4;
  int row0 = blockIdx.x * 32 + wave * 16;
  int mrow = row0 + n;

  floatx4 acc[16];
#pragma unroll
  for (int t = 0; t < 16; ++t) acc[t] = (floatx4){0.f, 0.f, 0.f, 0.f};

  for (int kc = 0; kc < KIN / 32; ++kc) {
    int k0 = kc * 32 + q * 8;
    short8 a = *(const short8*)(inA + (size_t)mrow * KIN + k0);
#pragma unroll
    for (int nt = 0; nt < 16; ++nt) {
      short8 b = *(const short8*)(wt + (size_t)(nt * 16 + n) * KIN + k0);
      acc[nt] = __builtin_amdgcn_mfma_f32_16x16x32_bf16(a, b, acc[nt], 0, 0, 0);
    }
  }

  int i0 = row0 + q * 4;
#pragma unroll
  for (int nt = 0; nt < 16; ++nt) {
    int c = nt * 16 + n;
    uintx2 pk;
    pk.x = f2bf(acc[nt][0]) | (f2bf(acc[nt][1]) << 16);
    pk.y = f2bf(acc[nt][2]) | (f2bf(acc[nt][3]) << 16);
    *(uintx2*)(ht + (size_t)c * NN + i0) = pk;
  }

  float s1[4] = {0.f, 0.f, 0.f, 0.f}, s2[4] = {0.f, 0.f, 0.f, 0.f};
#pragma unroll
  for (int nt = 0; nt < 16; ++nt) {
    float w1 = a1[nt * 16 + n];
    float w2 = a2[nt * 16 + n];
#pragma unroll
    for (int r = 0; r < 4; ++r) {
      s1[r] += acc[nt][r] * w1;
      s2[r] += acc[nt][r] * w2;
    }
  }
#pragma unroll
  for (int m = 1; m < 16; m <<= 1) {
#pragma unroll
    for (int r = 0; r < 4; ++r) {
      s1[r] += __shfl_xor(s1[r], m);
      s2[r] += __shfl_xor(s2[r], m);
    }
  }
  if (n == 0) {
#pragma unroll
    for (int r = 0; r < 4; ++r) {
      float v1 = s1[r], v2 = s2[r];
      e1[i0 + r] = v1;
      e2[i0 + r] = v2;
      A1[i0 + r] = __expf(v1 - 8.0f);
      A2[i0 + r] = __expf(0.25f * v1 - 8.0f);
      u32 b1 = f2bf(__expf(v2 - 8.0f));
      u32 b2 = f2bf(__expf(0.25f * v2 - 8.0f));
      e2pk[i0 + r] = (b1 << 16) | b2;
    }
  }
}

// ---------- K4 v6: R4's depth-2/4-buf/1-barrier + GROUPED adj loads ----------
// R5 post-mortem: attn is invariant ~100-125us across ALL schedules (direct,
// depth-1, depth-2, 4 blk/CU) — the one invariant is the adj DRAM pattern:
// 128B per row at 32KB stride, row revisited ~3us later -> every 128B line pays
// a DRAM page activation -> effective adj BW ~2.2 TB/s -> ~120us. Fix the
// ADDRESS STREAM, not the schedule: load adj for 4 chunks at once (16 intx4 per
// lane = contiguous 512B span per row, 4 consecutive lines back-to-back ->
// page-activation count /4). Same lane mapping, same p-compute, bit-identical
// output. vmcnt per body position (derivation in comments): steady k=0/1 -> 8,
// k=2/3 -> 24 (group in flight); edges ch=0->4, 28/29->8, 30->4, 31->0.
// Buffer-reuse safety = R4's 4-buffer argument (unchanged).
__global__ __launch_bounds__(256, 2)
void k_attn_v6(const int* __restrict__ adj, const unsigned short* __restrict__ ht,
               const float* __restrict__ A1, const float* __restrict__ A2,
               const u32* __restrict__ e2pk,
               __half2* __restrict__ oph, float* __restrict__ Dpart) {
  // LDS: 4 x 16K ht buffers | e2s 4K = 69632 B (2 blocks/CU)
  __shared__ __align__(16) char smem[69632];
  u32* e2s = (u32*)(smem + 65536);

  int b = blockIdx.x;
  int rg = b >> 3, js = b & 7;
  int wave = threadIdx.x >> 6, lane = threadIdx.x & 63;
  int n = lane & 15, q = lane >> 4;
  int rowbase = rg * 128 + wave * 32;
  int jbeg = js * 1024;
  int swz = q ^ ((n >> 1) & 3);          // bank-conflict-free B-frag read offset

  float A1v0 = A1[rowbase + n],      A2v0 = A2[rowbase + n];
  float A1v1 = A1[rowbase + 16 + n], A2v1 = A2[rowbase + 16 + n];

  floatx4 acc[2][16];
  floatx4 accd[2];
#pragma unroll
  for (int t = 0; t < 2; ++t) {
    accd[t] = (floatx4){0.f, 0.f, 0.f, 0.f};
#pragma unroll
    for (int nt = 0; nt < 16; ++nt) acc[t][nt] = (floatx4){0.f, 0.f, 0.f, 0.f};
  }

  union { uintx4 u; short8 s; } onesu;
  onesu.u = (uintx4){0x3F803F80u, 0x3F803F80u, 0x3F803F80u, 0x3F803F80u};
  short8 ones = onesu.s;

  const int* ar0 = adj + (size_t)(rowbase + n) * NN + jbeg + q * 8;
  const int* ar1 = adj + (size_t)(rowbase + 16 + n) * NN + jbeg + q * 8;

  // stage ht chunk ch into buf (4 DMA items/wave, pre-swizzled global source)
  auto stage = [&](int ch, int buf) {
    int j0g = jbeg + ch * 32;
    char* hbase = smem + buf * 16384;
#pragma unroll
    for (int i = 0; i < 4; ++i) {
      int seg = wave * 256 + i * 64 + lane;
      int c = seg >> 2;
      int o = (seg & 3) ^ ((seg >> 3) & 3);
      stage16(ht + (size_t)c * NN + j0g + o * 8, hbase + (size_t)(wave * 256 + i * 64) * 16);
    }
  };

  intx4 gA[16], gB[16];                  // two adj groups (4 chunks each), static-indexed

  // load adj group g (chunks 4g..4g+3): per lane 16 intx4, covering a CONTIGUOUS
  // 512B span of each of its two rows (4 consecutive 128B lines -> 1 page
  // activation per row per group instead of 4).
  auto ldgroup = [&](int g, intx4* arr) {
    const int* b0 = ar0 + g * 128;
    const int* b1 = ar1 + g * 128;
#pragma unroll
    for (int k = 0; k < 4; ++k) {
      arr[k * 4 + 0] = *(const intx4*)(b0 + k * 32);
      arr[k * 4 + 1] = *(const intx4*)(b0 + k * 32 + 4);
      arr[k * 4 + 2] = *(const intx4*)(b1 + k * 32);
      arr[k * 4 + 3] = *(const intx4*)(b1 + k * 32 + 4);
    }
  };

  // ---- prologue: e2s first (its auto-wait sees only its own load), then
  // stage(0), stage(1), group0 — all left in flight across the barrier ----
  uintx4 ev = *(const uintx4*)(e2pk + jbeg + threadIdx.x * 4);
  ((uintx4*)e2s)[threadIdx.x] = ev;      // compiler-inserted wait drains ev only
  asm volatile("" ::: "memory");
  stage(0, 0);
  stage(1, 1);
  ldgroup(0, gA);
  asm volatile("s_waitcnt lgkmcnt(0)" ::: "memory");  // e2s ds_write done
  asm volatile("s_barrier" ::: "memory");             // e2s visible; VMEM keeps flying

  // body: k = ch&3 (compile-time at every call site -> buf indices fold)
  auto body = [&](int ch, int k, intx4* aC, int wcnt, bool doStage, int gNext, intx4* aN) {
    if (doStage) stage(ch + 2, (k + 2) & 3);
    if (gNext >= 0) ldgroup(gNext, aN);

    // ---- p-compute chunk ch (adj regs landed >=2 bodies ago; e2s from LDS) ----
    uintx4 ba = *(const uintx4*)(e2s + ch * 32 + q * 8);
    uintx4 bb = *(const uintx4*)(e2s + ch * 32 + q * 8 + 4);
    u32 bw[8] = {ba.x, ba.y, ba.z, ba.w, bb.x, bb.y, bb.z, bb.w};

    float p0[8], p1[8];
#pragma unroll
    for (int jj = 0; jj < 8; ++jj) {
      int av0 = (jj < 4) ? aC[k * 4 + 0][jj] : aC[k * 4 + 1][jj - 4];
      int av1 = (jj < 4) ? aC[k * 4 + 2][jj] : aC[k * 4 + 3][jj - 4];
      float B1 = __uint_as_float(bw[jj] & 0xffff0000u);
      float B2 = __uint_as_float(bw[jj] << 16);
      float m10 = A1v0 * B1, m20 = A2v0 * B2;
      float m11 = A1v1 * B1, m21 = A2v1 * B2;
      float pm0 = fmaxf(m10, m20);                    // = exp(leakyrelu(e1+e2)-16)
      float pm1 = fmaxf(m11, m21);
      p0[jj] = (av0 != 0) ? pm0 : 0.f;
      p1[jj] = (av1 != 0) ? pm1 : 0.f;
    }
    short8 af0 = pack8(p0);
    short8 af1 = pack8(p1);

    // drain chunk ch's stage DMAs (+its adj group when due); newer stay in flight
    if (wcnt == 24)      asm volatile("s_waitcnt vmcnt(24)" ::: "memory");
    else if (wcnt == 8)  asm volatile("s_waitcnt vmcnt(8)" ::: "memory");
    else if (wcnt == 4)  asm volatile("s_waitcnt vmcnt(4)" ::: "memory");
    else                 asm volatile("s_waitcnt vmcnt(0)" ::: "memory");
    asm volatile("s_barrier" ::: "memory");           // all waves' quarters landed

    // B-frags from swizzled LDS tile
    const short8* lb = (const short8*)(smem + (size_t)k * 16384);
#pragma unroll
    for (int t = 0; t < 16; ++t) {
      short8 bfv = lb[t * 64 + n * 4 + swz];
      acc[0][t] = __builtin_amdgcn_mfma_f32_16x16x32_bf16(af0, bfv, acc[0][t], 0, 0, 0);
      acc[1][t] = __builtin_amdgcn_mfma_f32_16x16x32_bf16(af1, bfv, acc[1][t], 0, 0, 0);
    }
    accd[0] = __builtin_amdgcn_mfma_f32_16x16x32_bf16(af0, ones, accd[0], 0, 0, 0);
    accd[1] = __builtin_amdgcn_mfma_f32_16x16x32_bf16(af1, ones, accd[1], 0, 0, 0);
    // no trailing barrier: 4-buffer spacing makes reuse safe (R4 argument holds:
    // stage(ch+2) targets buf (k+2)&3, conflicting reads were chunk ch-2's,
    // which completed before their owner passed barrier(ch-1)).
  };

  // g=0 (edge waits: ch0 drains group0 -> vmcnt(4))
  body(0, 0, gA, 4,  true, -1, nullptr);
  body(1, 1, gA, 8,  true, -1, nullptr);
  body(2, 2, gA, 24, true, 1, gB);
  body(3, 3, gA, 24, true, -1, nullptr);
  for (int g = 1; g < 7; ++g) {
    int ch = g * 4;
    intx4* C = (g & 1) ? gB : gA;
    intx4* Nx = (g & 1) ? gA : gB;
    body(ch + 0, 0, C, 8,  true, -1, nullptr);
    body(ch + 1, 1, C, 8,  true, -1, nullptr);
    body(ch + 2, 2, C, 24, true, g + 1, Nx);
    body(ch + 3, 3, C, 24, true, -1, nullptr);
  }
  // g=7 tail: no more groups; stages end at ch=29 (stage(31))
  body(28, 0, gB, 8, true,  -1, nullptr);
  body(29, 1, gB, 8, true,  -1, nullptr);
  body(30, 2, gB, 4, false, -1, nullptr);
  body(31, 3, gB, 0, false, -1, nullptr);

  // denominator from accd C-layout: row = q*4+r (any col); lanes n==0 write
  if (n == 0) {
#pragma unroll
    for (int t2 = 0; t2 < 2; ++t2)
#pragma unroll
      for (int r = 0; r < 4; ++r)
        Dpart[(size_t)js * NN + rowbase + t2 * 16 + q * 4 + r] = accd[t2][r];
  }

  // numerator partials as half2 row-pairs: word (js*4096 + i/2)*256 + c
#pragma unroll
  for (int t2 = 0; t2 < 2; ++t2) {
    int ibase = rowbase + t2 * 16 + q * 4;            // multiple of 4
#pragma unroll
    for (int nt = 0; nt < 16; ++nt) {
      int c = nt * 16 + n;
      oph[((size_t)js * 4096 + (ibase >> 1)) * 256 + c] =
          __floats2half2_rn(acc[t2][nt][0], acc[t2][nt][1]);
      oph[((size_t)js * 4096 + (ibase >> 1) + 1) * 256 + c] =
          __floats2half2_rn(acc[t2][nt][2], acc[t2][nt][3]);
    }
  }
}

// ---------- K5: out = (sum_js oph)/(sum_js Dpart) + bias ----------
__global__ void k_final_part(float* __restrict__ out, const __half2* __restrict__ oph,
                             const float* __restrict__ Dpart, const float* __restrict__ bias) {
  int i = blockIdx.x;
  int c = threadIdx.x;
  int hi = i & 1;
  float s = 0.f, d = 0.f;
#pragma unroll
  for (int js = 0; js < 8; ++js) {
    __half2 h2 = oph[((size_t)js * 4096 + (i >> 1)) * 256 + c];
    s += hi ? __high2float(h2) : __low2float(h2);
    d += Dpart[(size_t)js * NN + i];
  }
  out[(size_t)i * COUT + c] = s / fmaxf(d, 1e-37f) + bias[c];
}

// ---------- Fallback path (atomics, direct adj) if ws is too small ----------
__global__ __launch_bounds__(256, 2)
void k_attn_atomic(const int* __restrict__ adj, const unsigned short* __restrict__ ht,
                   const float* __restrict__ e1, const float* __restrict__ e2,
                   float* __restrict__ out_num, float* __restrict__ Dbuf) {
  int b = blockIdx.x;
  int rg = b >> 3, js = b & 7;
  int wave = threadIdx.x >> 6, lane = threadIdx.x & 63;
  int n = lane & 15, q = lane >> 4;
  int rowbase = rg * 128 + wave * 32;

  float e1v0 = e1[rowbase + n];
  float e1v1 = e1[rowbase + 16 + n];

  floatx4 acc[2][16];
#pragma unroll
  for (int t = 0; t < 2; ++t)
#pragma unroll
    for (int nt = 0; nt < 16; ++nt) acc[t][nt] = (floatx4){0.f, 0.f, 0.f, 0.f};

  float d0 = 0.f, d1 = 0.f;
  int jbeg = js * 1024;

  for (int ch = 0; ch < 32; ++ch) {
    int j0 = jbeg + ch * 32 + q * 8;
    floatx4 ea = *(const floatx4*)(e2 + j0);
    floatx4 eb = *(const floatx4*)(e2 + j0 + 4);
    float ev[8] = {ea.x, ea.y, ea.z, ea.w, eb.x, eb.y, eb.z, eb.w};

    intx4 A00 = *(const intx4*)(adj + (size_t)(rowbase + n) * NN + j0);
    intx4 A01 = *(const intx4*)(adj + (size_t)(rowbase + n) * NN + j0 + 4);
    intx4 A10 = *(const intx4*)(adj + (size_t)(rowbase + 16 + n) * NN + j0);
    intx4 A11 = *(const intx4*)(adj + (size_t)(rowbase + 16 + n) * NN + j0 + 4);

    float p0[8], p1[8];
#pragma unroll
    for (int jj = 0; jj < 8; ++jj) {
      int av0 = (jj < 4) ? A00[jj] : A01[jj - 4];
      int av1 = (jj < 4) ? A10[jj] : A11[jj - 4];
      float t0 = e1v0 + ev[jj];
      float t1 = e1v1 + ev[jj];
      float f0 = fmaxf(t0, 0.25f * t0);
      float f1 = fmaxf(t1, 0.25f * t1);
      float x0 = __expf(f0 - SHIFT);
      float x1 = __expf(f1 - SHIFT);
      p0[jj] = (av0 != 0) ? x0 : 0.f;
      p1[jj] = (av1 != 0) ? x1 : 0.f;
      d0 += p0[jj];
      d1 += p1[jj];
    }
    short8 af0 = pack8(p0);
    short8 af1 = pack8(p1);

#pragma unroll
    for (int g = 0; g < 2; ++g) {
      short8 bf[8];
#pragma unroll
      for (int t = 0; t < 8; ++t)
        bf[t] = *(const short8*)(ht + (size_t)((g * 8 + t) * 16 + n) * NN + j0);
#pragma unroll
      for (int t = 0; t < 8; ++t) {
        acc[0][g * 8 + t] = __builtin_amdgcn_mfma_f32_16x16x32_bf16(af0, bf[t], acc[0][g * 8 + t], 0, 0, 0);
        acc[1][g * 8 + t] = __builtin_amdgcn_mfma_f32_16x16x32_bf16(af1, bf[t], acc[1][g * 8 + t], 0, 0, 0);
      }
    }
  }

  d0 += __shfl_xor(d0, 16); d0 += __shfl_xor(d0, 32);
  d1 += __shfl_xor(d1, 16); d1 += __shfl_xor(d1, 32);
  if (lane < 16) {
    atomicAdd(Dbuf + rowbase + lane, d0);
    atomicAdd(Dbuf + rowbase + 16 + lane, d1);
  }

#pragma unroll
  for (int t2 = 0; t2 < 2; ++t2) {
#pragma unroll
    for (int nt = 0; nt < 16; ++nt) {
#pragma unroll
      for (int r = 0; r < 4; ++r) {
        int i = rowbase + t2 * 16 + q * 4 + r;
        atomicAdd(out_num + (size_t)i * COUT + nt * 16 + n, acc[t2][nt][r]);
      }
    }
  }
}

__global__ void k_final_atomic(float* __restrict__ out, const float* __restrict__ Dbuf,
                               const float* __restrict__ bias) {
  int idx = blockIdx.x * 256 + threadIdx.x;
  int i = idx >> 8, c = idx & 255;
  float d = fmaxf(Dbuf[i], 1e-37f);
  out[idx] = out[idx] / d + bias[c];
}

// ---------- launch ----------
extern "C" void kernel_launch(void* const* d_in, const int* in_sizes, int n_in,
                              void* d_out, int out_size, void* d_ws, size_t ws_size,
                              hipStream_t stream) {
  const float* input   = (const float*)d_in[0];
  const int*   adj     = (const int*)d_in[1];
  const float* weights = (const float*)d_in[2];
  const float* a1      = (const float*)d_in[3];
  const float* a2      = (const float*)d_in[4];
  const float* bias    = (const float*)d_in[5];
  float* out = (float*)d_out;
  char* ws = (char*)d_ws;

  unsigned short* inA = (unsigned short*)(ws);                 // 8 MB   [8192][512] bf16
  unsigned short* wt  = (unsigned short*)(ws + 8388608);       // 256 KB [256][512] bf16
  unsigned short* ht  = (unsigned short*)(ws + 8650752);       // 4 MB   [256][8192] bf16
  float* e1    = (float*)(ws + 12845056);                      // 32 KB
  float* e2    = (float*)(ws + 12877824);                      // 32 KB
  float* A1    = (float*)(ws + 12910592);                      // 32 KB exp(e1-8)
  float* A2    = (float*)(ws + 12943360);                      // 32 KB exp(.25e1-8)
  u32*   e2pk  = (u32*)  (ws + 12976128);                      // 32 KB packed B1|B2
  float* Dpart = (float*)(ws + 13008896);                      // 256 KB [8][8192]
  __half2* oph = (__half2*)(ws + 13271040);                    // 32 MB  [8][4096][256] half2
  const size_t WS_NEEDED_PART = 13271040 + (size_t)8 * NN * COUT * 2;  // ~45 MB
  float* Dbuf = Dpart;

  k_prep<<<4608, 256, 0, stream>>>(input, (ushortx4*)inA, weights, wt);
  k_gemm_h<<<256, 128, 0, stream>>>(inA, wt, a1, a2, ht, e1, e2, A1, A2, e2pk);

  if (ws_size >= WS_NEEDED_PART) {
    k_attn_v6<<<512, 256, 0, stream>>>(adj, ht, A1, A2, e2pk, oph, Dpart);
    k_final_part<<<8192, 256, 0, stream>>>(out, oph, Dpart, bias);
  } else {
    hipMemsetAsync(out, 0, (size_t)NN * COUT * sizeof(float), stream);
    hipMemsetAsync(Dbuf, 0, NN * sizeof(float), stream);
    k_attn_atomic<<<512, 256, 0, stream>>>(adj, ht, e1, e2, out, Dbuf);
    k_final_atomic<<<8192, 256, 0, stream>>>(out, Dbuf, bias);
  }
}

// Round 8
// 437.209 us; speedup vs baseline: 1.9830x; 1.9830x over previous
//
#include <hip/hip_runtime.h>
#include <hip/hip_fp16.h>

typedef __attribute__((ext_vector_type(8))) short short8;
typedef __attribute__((ext_vector_type(4))) float floatx4;
typedef __attribute__((ext_vector_type(4))) unsigned int uintx4;
typedef __attribute__((ext_vector_type(2))) unsigned int uintx2;
typedef __attribute__((ext_vector_type(4))) int intx4;
typedef __attribute__((ext_vector_type(4))) unsigned short ushortx4;
typedef unsigned int u32;

#define NN 8192
#define KIN 512
#define COUT 256
#define SHIFT 16.0f

#define AS1 __attribute__((address_space(1)))
#define AS3 __attribute__((address_space(3)))

// async global->LDS, 16B per lane; LDS base wave-uniform, lane lands at +lane*16
__device__ __forceinline__ void stage16(const void* g, void* l) {
  __builtin_amdgcn_global_load_lds((const AS1 u32*)g, (AS3 u32*)l, 16, 0, 0);
}

// ---------- helpers ----------
__device__ __forceinline__ unsigned int f2bf(float f) {
  unsigned int u = __float_as_uint(f);
  return (u + 0x7FFFu + ((u >> 16) & 1u)) >> 16;  // RNE round to bf16
}

// pack two fp32 -> bf16 pair (round-half-up + byte-perm; p>=0, never NaN here)
__device__ __forceinline__ u32 pkbf(float lo, float hi) {
  u32 a = __float_as_uint(lo) + 0x8000u;
  u32 b = __float_as_uint(hi) + 0x8000u;
  return __builtin_amdgcn_perm(b, a, 0x07060302u);  // [hi.b3 hi.b2 lo.b3 lo.b2]
}

__device__ __forceinline__ short8 pack8(const float* p) {
  uintx4 w;
  w.x = pkbf(p[0], p[1]);
  w.y = pkbf(p[2], p[3]);
  w.z = pkbf(p[4], p[5]);
  w.w = pkbf(p[6], p[7]);
  union { uintx4 u; short8 s; } cv; cv.u = w;
  return cv.s;
}

// ---------- K1 merged: cast input fp32->bf16, transpose weights (R4 form) ----------
__global__ __launch_bounds__(256)
void k_prep(const float* __restrict__ in, ushortx4* __restrict__ inA4,
            const float* __restrict__ w, unsigned short* __restrict__ wt) {
  int b = blockIdx.x;
  if (b < 4096) {
    int idx = b * 256 + threadIdx.x;
    floatx4 v = ((const floatx4*)in)[idx];
    ushortx4 o;
    o.x = (unsigned short)f2bf(v.x);
    o.y = (unsigned short)f2bf(v.y);
    o.z = (unsigned short)f2bf(v.z);
    o.w = (unsigned short)f2bf(v.w);
    inA4[idx] = o;
  } else {
    int idx = (b - 4096) * 256 + threadIdx.x;
    int k = idx >> 8, c = idx & 255;
    wt[c * KIN + k] = (unsigned short)f2bf(w[idx]);
  }
}

// ---------- K2: h = X*W via MFMA (R4 form: bf16 inA, 256 blocks x 128 thr) ----------
__global__ __launch_bounds__(128)
void k_gemm_h(const unsigned short* __restrict__ inA, const unsigned short* __restrict__ wt,
              const float* __restrict__ a1, const float* __restrict__ a2,
              unsigned short* __restrict__ ht, float* __restrict__ e1, float* __restrict__ e2,
              float* __restrict__ A1, float* __restrict__ A2, u32* __restrict__ e2pk) {
  int wave = threadIdx.x >> 6;          // 0..1
  int lane = threadIdx.x & 63;
  int n = lane & 15, q = lane >> 4;
  int row0 = blockIdx.x * 32 + wave * 16;
  int mrow = row0 + n;

  floatx4 acc[16];
#pragma unroll
  for (int t = 0; t < 16; ++t) acc[t] = (floatx4){0.f, 0.f, 0.f, 0.f};

  for (int kc = 0; kc < KIN / 32; ++kc) {
    int k0 = kc * 32 + q * 8;
    short8 a = *(const short8*)(inA + (size_t)mrow * KIN + k0);
#pragma unroll
    for (int nt = 0; nt < 16; ++nt) {
      short8 b = *(const short8*)(wt + (size_t)(nt * 16 + n) * KIN + k0);
      acc[nt] = __builtin_amdgcn_mfma_f32_16x16x32_bf16(a, b, acc[nt], 0, 0, 0);
    }
  }

  int i0 = row0 + q * 4;
#pragma unroll
  for (int nt = 0; nt < 16; ++nt) {
    int c = nt * 16 + n;
    uintx2 pk;
    pk.x = f2bf(acc[nt][0]) | (f2bf(acc[nt][1]) << 16);
    pk.y = f2bf(acc[nt][2]) | (f2bf(acc[nt][3]) << 16);
    *(uintx2*)(ht + (size_t)c * NN + i0) = pk;
  }

  float s1[4] = {0.f, 0.f, 0.f, 0.f}, s2[4] = {0.f, 0.f, 0.f, 0.f};
#pragma unroll
  for (int nt = 0; nt < 16; ++nt) {
    float w1 = a1[nt * 16 + n];
    float w2 = a2[nt * 16 + n];
#pragma unroll
    for (int r = 0; r < 4; ++r) {
      s1[r] += acc[nt][r] * w1;
      s2[r] += acc[nt][r] * w2;
    }
  }
#pragma unroll
  for (int m = 1; m < 16; m <<= 1) {
#pragma unroll
    for (int r = 0; r < 4; ++r) {
      s1[r] += __shfl_xor(s1[r], m);
      s2[r] += __shfl_xor(s2[r], m);
    }
  }
  if (n == 0) {
#pragma unroll
    for (int r = 0; r < 4; ++r) {
      float v1 = s1[r], v2 = s2[r];
      e1[i0 + r] = v1;
      e2[i0 + r] = v2;
      A1[i0 + r] = __expf(v1 - 8.0f);
      A2[i0 + r] = __expf(0.25f * v1 - 8.0f);
      u32 b1 = f2bf(__expf(v2 - 8.0f));
      u32 b2 = f2bf(__expf(0.25f * v2 - 8.0f));
      e2pk[i0 + r] = (b1 << 16) | b2;
    }
  }
}

// ---------- K4 v7: 64-col chunks, 8-wave block, 1 barrier/chunk ----------
// (Resubmission: R7 bench failed at container level with no kernel execution;
//  audit found no hang/spill/limit mechanism — no divergent barriers, no
//  runtime-indexed register arrays (R6's spill was the runtime-TERNARY-selected
//  array pointer, absent here), LDS 132KB < 160KB gfx950 limit.)
// Ledger: adj stream already at full HBM BW (R4-R1 delta = 44us = 268MB @
// 6.1TB/s); residual = adj-free CORE ~79us vs ~30us pipe work — invariant
// because every variant kept 32 chunks x {vmcnt+barrier+loop} fixed cost.
// v7 halves chunk COUNT (16 x 64-col), one 512-thr block (8 waves x 16 rows):
// 4 x 32KB LDS bufs + 4KB e2s = 132KB -> 1 block/CU (2 waves/SIMD, same as
// before), ONE barrier/chunk -> 17 barriers (vs 33), 16 vmcnt waits (vs 32).
// Totals (MFMA/LDS/adj/VALU) unchanged; bit-identical math.
// Swizzle (64-wide): stage writes LDS[row*8+s] = ht[row][j0g+(s^(row&7))*8];
// read slot s=(h*4+q)^(n&7) returns col-oct h*4+q; lanes spread uniformly over
// all 8 bank-quads (LDS throughput floor).
// Buffer safety (1 barrier): stage(ch+2) targets buf (ch+2)&3; the only waves
// that could still be reading it finished chunk ch-2's reads (lgkm-before-mfma)
// before passing barrier(ch-1), which precedes stage(ch+2)'s issue.
// vmcnt: steady 16 = 2 bodies x 8 ops in flight; edges 8 (ch=14), 0 (ch=15).
__global__ __launch_bounds__(512, 2)
void k_attn_v7(const int* __restrict__ adj, const unsigned short* __restrict__ ht,
               const float* __restrict__ A1, const float* __restrict__ A2,
               const u32* __restrict__ e2pk,
               __half2* __restrict__ oph, float* __restrict__ Dpart) {
  // LDS: 4 x 32K ht buffers | e2s 4K = 135168 B (1 block/CU)
  __shared__ __align__(16) char smem[135168];
  u32* e2s = (u32*)(smem + 131072);

  int b = blockIdx.x;
  int rg = b >> 3, js = b & 7;
  int wave = threadIdx.x >> 6, lane = threadIdx.x & 63;
  int n = lane & 15, q = lane >> 4;
  int rowbase = rg * 128 + wave * 16;    // 16 rows per wave, 8 waves = 128 rows
  int jbeg = js * 1024;

  float A1v = A1[rowbase + n], A2v = A2[rowbase + n];

  floatx4 acc[16];
  floatx4 accd = (floatx4){0.f, 0.f, 0.f, 0.f};
#pragma unroll
  for (int t = 0; t < 16; ++t) acc[t] = (floatx4){0.f, 0.f, 0.f, 0.f};

  union { uintx4 u; short8 s; } onesu;
  onesu.u = (uintx4){0x3F803F80u, 0x3F803F80u, 0x3F803F80u, 0x3F803F80u};
  short8 ones = onesu.s;

  const int* ar = adj + (size_t)(rowbase + n) * NN + jbeg + q * 8;

  // stage ht chunk ch (64 cols) into buf: 4 DMA/wave, pre-swizzled global source
  auto stage = [&](int ch, int buf) {
    int j0g = jbeg + ch * 64;
    char* hbase = smem + buf * 32768;
#pragma unroll
    for (int i = 0; i < 4; ++i) {
      int seg = wave * 256 + i * 64 + lane;
      int row = seg >> 3;
      int o = (seg & 7) ^ (row & 7);
      stage16(ht + (size_t)row * NN + j0g + o * 8,
              hbase + (size_t)(wave * 256 + i * 64) * 16);
    }
  };

  // adj for chunk ch: per lane ONE row, halves h0 (cols q*8) / h1 (cols 32+q*8)
  auto ldadj = [&](int ch, intx4* A) {
    const int* p = ar + ch * 64;
    A[0] = *(const intx4*)(p);
    A[1] = *(const intx4*)(p + 4);
    A[2] = *(const intx4*)(p + 32);
    A[3] = *(const intx4*)(p + 36);
  };

  intx4 aA[4], aB[4];                    // even / odd chunk adj sets (literal idx only)

  // ---- prologue: e2s first (its auto-wait drains nothing else), then pipeline ----
  uintx2 ev = *(const uintx2*)(e2pk + jbeg + threadIdx.x * 2);
  ((uintx2*)e2s)[threadIdx.x] = ev;      // compiler waits on ev only
  asm volatile("" ::: "memory");
  stage(0, 0);
  ldadj(0, aA);
  stage(1, 1);
  ldadj(1, aB);
  asm volatile("s_waitcnt lgkmcnt(0)" ::: "memory");  // e2s ds_write done
  asm volatile("s_barrier" ::: "memory");             // e2s visible; 16 VMEM keep flying

  auto body = [&](int ch, intx4* aC, int wcnt, bool doPf) {
    if (doPf) stage(ch + 2, (ch + 2) & 3);

    // ---- p-compute both k-halves (regs + e2s; independent of in-flight DMA) ----
    short8 af0, af1;
#pragma unroll
    for (int h = 0; h < 2; ++h) {
      uintx4 ba = *(const uintx4*)(e2s + ch * 64 + h * 32 + q * 8);
      uintx4 bb = *(const uintx4*)(e2s + ch * 64 + h * 32 + q * 8 + 4);
      u32 bw[8] = {ba.x, ba.y, ba.z, ba.w, bb.x, bb.y, bb.z, bb.w};
      intx4 w0 = (h == 0) ? aC[0] : aC[2];
      intx4 w1 = (h == 0) ? aC[1] : aC[3];
      float p0[8];
#pragma unroll
      for (int jj = 0; jj < 8; ++jj) {
        int av = (jj < 4) ? w0[jj] : w1[jj - 4];
        float B1 = __uint_as_float(bw[jj] & 0xffff0000u);
        float B2 = __uint_as_float(bw[jj] << 16);
        float pm = fmaxf(A1v * B1, A2v * B2);         // = exp(leakyrelu(e1+e2)-16)
        p0[jj] = (av != 0) ? pm : 0.f;
      }
      if (h == 0) af0 = pack8(p0); else af1 = pack8(p0);
    }

    if (doPf) ldadj(ch + 2, aC);                      // reload consumed set

    // drain chunk ch's 8 ops (stage+adj, issued 2 bodies ago); newest 16 in flight
    if (wcnt == 16)     asm volatile("s_waitcnt vmcnt(16)" ::: "memory");
    else if (wcnt == 8) asm volatile("s_waitcnt vmcnt(8)" ::: "memory");
    else                asm volatile("s_waitcnt vmcnt(0)" ::: "memory");
    asm volatile("s_barrier" ::: "memory");           // all waves' segments landed

    // B-frags from swizzled 64-wide tile: short8 idx = (t*16+n)*8 + ((h*4+q)^(n&7))
    const short8* lb = (const short8*)(smem + (size_t)(ch & 3) * 32768);
#pragma unroll
    for (int t = 0; t < 16; ++t) {
      short8 bfv = lb[(t * 16 + n) * 8 + ((q) ^ (n & 7))];
      acc[t] = __builtin_amdgcn_mfma_f32_16x16x32_bf16(af0, bfv, acc[t], 0, 0, 0);
    }
    accd = __builtin_amdgcn_mfma_f32_16x16x32_bf16(af0, ones, accd, 0, 0, 0);
#pragma unroll
    for (int t = 0; t < 16; ++t) {
      short8 bfv = lb[(t * 16 + n) * 8 + ((4 + q) ^ (n & 7))];
      acc[t] = __builtin_amdgcn_mfma_f32_16x16x32_bf16(af1, bfv, acc[t], 0, 0, 0);
    }
    accd = __builtin_amdgcn_mfma_f32_16x16x32_bf16(af1, ones, accd, 0, 0, 0);
    // no trailing barrier: 4-buffer spacing (see header safety argument)
  };

  for (int c2 = 0; c2 < 14; c2 += 2) {
    body(c2, aA, 16, true);
    body(c2 + 1, aB, 16, true);
  }
  body(14, aA, 8, false);
  body(15, aB, 0, false);

  // denominator from accd C-layout: row = q*4+r (any col); lanes n==0 write
  if (n == 0) {
#pragma unroll
    for (int r = 0; r < 4; ++r)
      Dpart[(size_t)js * NN + rowbase + q * 4 + r] = accd[r];
  }

  // numerator partials as half2 row-pairs: word (js*4096 + i/2)*256 + c
  int ibase = rowbase + q * 4;                        // multiple of 4
#pragma unroll
  for (int t = 0; t < 16; ++t) {
    int c = t * 16 + n;
    oph[((size_t)js * 4096 + (ibase >> 1)) * 256 + c] =
        __floats2half2_rn(acc[t][0], acc[t][1]);
    oph[((size_t)js * 4096 + (ibase >> 1) + 1) * 256 + c] =
        __floats2half2_rn(acc[t][2], acc[t][3]);
  }
}

// ---------- K5: out = (sum_js oph)/(sum_js Dpart) + bias ----------
__global__ void k_final_part(float* __restrict__ out, const __half2* __restrict__ oph,
                             const float* __restrict__ Dpart, const float* __restrict__ bias) {
  int i = blockIdx.x;
  int c = threadIdx.x;
  int hi = i & 1;
  float s = 0.f, d = 0.f;
#pragma unroll
  for (int js = 0; js < 8; ++js) {
    __half2 h2 = oph[((size_t)js * 4096 + (i >> 1)) * 256 + c];
    s += hi ? __high2float(h2) : __low2float(h2);
    d += Dpart[(size_t)js * NN + i];
  }
  out[(size_t)i * COUT + c] = s / fmaxf(d, 1e-37f) + bias[c];
}

// ---------- Fallback path (atomics, direct adj) if ws is too small ----------
__global__ __launch_bounds__(256, 2)
void k_attn_atomic(const int* __restrict__ adj, const unsigned short* __restrict__ ht,
                   const float* __restrict__ e1, const float* __restrict__ e2,
                   float* __restrict__ out_num, float* __restrict__ Dbuf) {
  int b = blockIdx.x;
  int rg = b >> 3, js = b & 7;
  int wave = threadIdx.x >> 6, lane = threadIdx.x & 63;
  int n = lane & 15, q = lane >> 4;
  int rowbase = rg * 128 + wave * 32;

  float e1v0 = e1[rowbase + n];
  float e1v1 = e1[rowbase + 16 + n];

  floatx4 acc[2][16];
#pragma unroll
  for (int t = 0; t < 2; ++t)
#pragma unroll
    for (int nt = 0; nt < 16; ++nt) acc[t][nt] = (floatx4){0.f, 0.f, 0.f, 0.f};

  float d0 = 0.f, d1 = 0.f;
  int jbeg = js * 1024;

  for (int ch = 0; ch < 32; ++ch) {
    int j0 = jbeg + ch * 32 + q * 8;
    floatx4 ea = *(const floatx4*)(e2 + j0);
    floatx4 eb = *(const floatx4*)(e2 + j0 + 4);
    float ev[8] = {ea.x, ea.y, ea.z, ea.w, eb.x, eb.y, eb.z, eb.w};

    intx4 A00 = *(const intx4*)(adj + (size_t)(rowbase + n) * NN + j0);
    intx4 A01 = *(const intx4*)(adj + (size_t)(rowbase + n) * NN + j0 + 4);
    intx4 A10 = *(const intx4*)(adj + (size_t)(rowbase + 16 + n) * NN + j0);
    intx4 A11 = *(const intx4*)(adj + (size_t)(rowbase + 16 + n) * NN + j0 + 4);

    float p0[8], p1[8];
#pragma unroll
    for (int jj = 0; jj < 8; ++jj) {
      int av0 = (jj < 4) ? A00[jj] : A01[jj - 4];
      int av1 = (jj < 4) ? A10[jj] : A11[jj - 4];
      float t0 = e1v0 + ev[jj];
      float t1 = e1v1 + ev[jj];
      float f0 = fmaxf(t0, 0.25f * t0);
      float f1 = fmaxf(t1, 0.25f * t1);
      float x0 = __expf(f0 - SHIFT);
      float x1 = __expf(f1 - SHIFT);
      p0[jj] = (av0 != 0) ? x0 : 0.f;
      p1[jj] = (av1 != 0) ? x1 : 0.f;
      d0 += p0[jj];
      d1 += p1[jj];
    }
    short8 af0 = pack8(p0);
    short8 af1 = pack8(p1);

#pragma unroll
    for (int g = 0; g < 2; ++g) {
      short8 bf[8];
#pragma unroll
      for (int t = 0; t < 8; ++t)
        bf[t] = *(const short8*)(ht + (size_t)((g * 8 + t) * 16 + n) * NN + j0);
#pragma unroll
      for (int t = 0; t < 8; ++t) {
        acc[0][g * 8 + t] = __builtin_amdgcn_mfma_f32_16x16x32_bf16(af0, bf[t], acc[0][g * 8 + t], 0, 0, 0);
        acc[1][g * 8 + t] = __builtin_amdgcn_mfma_f32_16x16x32_bf16(af1, bf[t], acc[1][g * 8 + t], 0, 0, 0);
      }
    }
  }

  d0 += __shfl_xor(d0, 16); d0 += __shfl_xor(d0, 32);
  d1 += __shfl_xor(d1, 16); d1 += __shfl_xor(d1, 32);
  if (lane < 16) {
    atomicAdd(Dbuf + rowbase + lane, d0);
    atomicAdd(Dbuf + rowbase + 16 + lane, d1);
  }

#pragma unroll
  for (int t2 = 0; t2 < 2; ++t2) {
#pragma unroll
    for (int nt = 0; nt < 16; ++nt) {
#pragma unroll
      for (int r = 0; r < 4; ++r) {
        int i = rowbase + t2 * 16 + q * 4 + r;
        atomicAdd(out_num + (size_t)i * COUT + nt * 16 + n, acc[t2][nt][r]);
      }
    }
  }
}

__global__ void k_final_atomic(float* __restrict__ out, const float* __restrict__ Dbuf,
                               const float* __restrict__ bias) {
  int idx = blockIdx.x * 256 + threadIdx.x;
  int i = idx >> 8, c = idx & 255;
  float d = fmaxf(Dbuf[i], 1e-37f);
  out[idx] = out[idx] / d + bias[c];
}

// ---------- launch ----------
extern "C" void kernel_launch(void* const* d_in, const int* in_sizes, int n_in,
                              void* d_out, int out_size, void* d_ws, size_t ws_size,
                              hipStream_t stream) {
  const float* input   = (const float*)d_in[0];
  const int*   adj     = (const int*)d_in[1];
  const float* weights = (const float*)d_in[2];
  const float* a1      = (const float*)d_in[3];
  const float* a2      = (const float*)d_in[4];
  const float* bias    = (const float*)d_in[5];
  float* out = (float*)d_out;
  char* ws = (char*)d_ws;

  unsigned short* inA = (unsigned short*)(ws);                 // 8 MB   [8192][512] bf16
  unsigned short* wt  = (unsigned short*)(ws + 8388608);       // 256 KB [256][512] bf16
  unsigned short* ht  = (unsigned short*)(ws + 8650752);       // 4 MB   [256][8192] bf16
  float* e1    = (float*)(ws + 12845056);                      // 32 KB
  float* e2    = (float*)(ws + 12877824);                      // 32 KB
  float* A1    = (float*)(ws + 12910592);                      // 32 KB exp(e1-8)
  float* A2    = (float*)(ws + 12943360);                      // 32 KB exp(.25e1-8)
  u32*   e2pk  = (u32*)  (ws + 12976128);                      // 32 KB packed B1|B2
  float* Dpart = (float*)(ws + 13008896);                      // 256 KB [8][8192]
  __half2* oph = (__half2*)(ws + 13271040);                    // 32 MB  [8][4096][256] half2
  const size_t WS_NEEDED_PART = 13271040 + (size_t)8 * NN * COUT * 2;  // ~45 MB
  float* Dbuf = Dpart;

  k_prep<<<4608, 256, 0, stream>>>(input, (ushortx4*)inA, weights, wt);
  k_gemm_h<<<256, 128, 0, stream>>>(inA, wt, a1, a2, ht, e1, e2, A1, A2, e2pk);

  if (ws_size >= WS_NEEDED_PART) {
    k_attn_v7<<<512, 512, 0, stream>>>(adj, ht, A1, A2, e2pk, oph, Dpart);
    k_final_part<<<8192, 256, 0, stream>>>(out, oph, Dpart, bias);
  } else {
    hipMemsetAsync(out, 0, (size_t)NN * COUT * sizeof(float), stream);
    hipMemsetAsync(Dbuf, 0, NN * sizeof(float), stream);
    k_attn_atomic<<<512, 256, 0, stream>>>(adj, ht, e1, e2, out, Dbuf);
    k_final_atomic<<<8192, 256, 0, stream>>>(out, Dbuf, bias);
  }
}